// Round 1
// baseline (1997.569 us; speedup 1.0000x reference)
//
#include <hip/hip_runtime.h>

#define DEVI static __device__ __forceinline__

constexpr int B = 8;
constexpr int N0 = 4096;
constexpr int KNB = 64;

// d2 exactly as numpy: ((dx*dx + dy*dy) + dz*dz), no FMA contraction.
DEVI float dist2f(float ax, float ay, float az, float bx, float by, float bz) {
#pragma clang fp contract(off)
  float dx = ax - bx;
  float dy = ay - by;
  float dz = az - bz;
  return (dx * dx + dy * dy) + dz * dz;
}

// argmax key: max d wins, ties -> lowest index
DEVI unsigned long long packMaxKey(float v, int i) {
  return ((unsigned long long)__float_as_uint(v) << 32) |
         (unsigned int)(0x7fffffff - i);
}
// argmin key: min d wins, ties -> lowest index
DEVI unsigned long long packMinKey(float v, int i) {
  return ((unsigned long long)__float_as_uint(v) << 32) | (unsigned int)i;
}
DEVI unsigned long long shflXorU64(unsigned long long v, int m) {
  unsigned int lo = (unsigned int)v;
  unsigned int hi = (unsigned int)(v >> 32);
  lo = __shfl_xor(lo, m, 64);
  hi = __shfl_xor(hi, m, 64);
  return ((unsigned long long)hi << 32) | lo;
}

// ---------------- embedding + point_id_emb ----------------
__global__ void __launch_bounds__(256) x0_kernel(const int* __restrict__ feat,
                                                 const float* __restrict__ emb,
                                                 const float* __restrict__ pid,
                                                 float* __restrict__ x0) {
  int gid = blockIdx.x * 256 + threadIdx.x;  // over B*N0*32
  if (gid >= B * N0 * 32) return;
  int c = gid & 31;
  int bn = gid >> 5;
  int n = bn & (N0 - 1);
  int f = feat[bn];
  float v = emb[f * 32 + c];
  if (n < 1024) v += pid[n * 32 + c];
  x0[gid] = v;
}

// ---------------- farthest point sampling ----------------
template <int NPTS, int M, int BLK>
__global__ void __launch_bounds__(BLK) fps_kernel(const float* __restrict__ pos,
                                                  int* __restrict__ idx_out,
                                                  float* __restrict__ pos_out) {
  constexpr int EPT = NPTS / BLK;
  constexpr int NW = BLK / 64;
  __shared__ unsigned long long red[2][NW];
  const int b = blockIdx.x;
  const int t = threadIdx.x;
  const float* pb = pos + (size_t)b * NPTS * 3;
  float px[EPT], py[EPT], pz[EPT], d[EPT];
#pragma unroll
  for (int e = 0; e < EPT; ++e) {
    int i = t + e * BLK;
    px[e] = pb[i * 3 + 0];
    py[e] = pb[i * 3 + 1];
    pz[e] = pb[i * 3 + 2];
  }
  float sx = pb[0], sy = pb[1], sz = pb[2];
  if (t == 0) {
    idx_out[b * M + 0] = 0;
    pos_out[(size_t)(b * M + 0) * 3 + 0] = sx;
    pos_out[(size_t)(b * M + 0) * 3 + 1] = sy;
    pos_out[(size_t)(b * M + 0) * 3 + 2] = sz;
  }
  unsigned long long lkey = 0ULL;
#pragma unroll
  for (int e = 0; e < EPT; ++e) {
    float v = dist2f(px[e], py[e], pz[e], sx, sy, sz);
    d[e] = v;
    unsigned long long kk = packMaxKey(v, t + e * BLK);
    lkey = (lkey > kk) ? lkey : kk;
  }
  for (int it = 1; it < M; ++it) {
    unsigned long long k = lkey;
#pragma unroll
    for (int off = 32; off > 0; off >>= 1) {
      unsigned long long o = shflXorU64(k, off);
      k = (k > o) ? k : o;
    }
    if ((t & 63) == 0) red[it & 1][t >> 6] = k;
    __syncthreads();
    k = red[it & 1][0];
#pragma unroll
    for (int w = 1; w < NW; ++w) {
      unsigned long long o = red[it & 1][w];
      k = (k > o) ? k : o;
    }
    const int sel = 0x7fffffff - (int)(unsigned int)(k & 0xffffffffULL);
    sx = pb[sel * 3 + 0];
    sy = pb[sel * 3 + 1];
    sz = pb[sel * 3 + 2];
    if (t == 0) {
      idx_out[b * M + it] = sel;
      pos_out[(size_t)(b * M + it) * 3 + 0] = sx;
      pos_out[(size_t)(b * M + it) * 3 + 1] = sy;
      pos_out[(size_t)(b * M + it) * 3 + 2] = sz;
    }
    lkey = 0ULL;
#pragma unroll
    for (int e = 0; e < EPT; ++e) {
      float nd = dist2f(px[e], py[e], pz[e], sx, sy, sz);
      float v = fminf(d[e], nd);
      d[e] = v;
      unsigned long long kk = packMaxKey(v, t + e * BLK);
      lkey = (lkey > kk) ? lkey : kk;
    }
  }
}

// ---------------- radius neighbors (<=64 nearest within r) ----------------
template <int NPTS, int M>
__global__ void __launch_bounds__(256) radius_kernel(const float* __restrict__ pos,
                                                     const float* __restrict__ pos_s,
                                                     float r2,
                                                     int* __restrict__ nbr,
                                                     int* __restrict__ cnt) {
  __shared__ float d2s[NPTS];
  __shared__ unsigned long long red[4];
  __shared__ int ctr;
  const float INFV = __builtin_inff();
  const int blk = blockIdx.x;
  const int t = threadIdx.x;
  const int b = blk / M;
  const float* pb = pos + (size_t)b * NPTS * 3;
  const float cx = pos_s[(size_t)blk * 3 + 0];
  const float cy = pos_s[(size_t)blk * 3 + 1];
  const float cz = pos_s[(size_t)blk * 3 + 2];
  if (t == 0) ctr = 0;
  __syncthreads();
  for (int j = t; j < NPTS; j += 256) {
    float d2 = dist2f(pb[j * 3 + 0], pb[j * 3 + 1], pb[j * 3 + 2], cx, cy, cz);
    d2s[j] = (d2 <= r2) ? d2 : INFV;
  }
  __syncthreads();
  for (int j = t; j < NPTS; j += 256) {
    if (d2s[j] < INFV) {
      int p = atomicAdd(&ctr, 1);
      if (p < KNB) nbr[(size_t)blk * KNB + p] = j;
    }
  }
  __syncthreads();
  const int c = ctr;
  if (c <= KNB) {
    if (t == 0) cnt[blk] = c;
    return;
  }
  // overflow: exact 64-nearest, ties -> lower index (matches lax.top_k)
  for (int k = 0; k < KNB; ++k) {
    unsigned long long lk = ~0ULL;
    for (int j = t; j < NPTS; j += 256) {
      unsigned long long kk = packMinKey(d2s[j], j);
      lk = (lk < kk) ? lk : kk;
    }
#pragma unroll
    for (int off = 32; off > 0; off >>= 1) {
      unsigned long long o = shflXorU64(lk, off);
      lk = (lk < o) ? lk : o;
    }
    if ((t & 63) == 0) red[t >> 6] = lk;
    __syncthreads();
    lk = red[0];
#pragma unroll
    for (int w = 1; w < 4; ++w) {
      unsigned long long o = red[w];
      lk = (lk < o) ? lk : o;
    }
    int idx = (int)(unsigned int)(lk & 0xffffffffULL);
    if (t == 0) {
      nbr[(size_t)blk * KNB + k] = idx;
      d2s[idx] = INFV;
    }
    __syncthreads();
  }
  if (t == 0) cnt[blk] = KNB;
}

// ---------------- stage 1 conv: 35 -> 64 -> 64 -> 64, max over nbrs ----------------
__global__ void __launch_bounds__(64) conv1_kernel(
    const float* __restrict__ x0, const float* __restrict__ pos,
    const float* __restrict__ pos_s, const int* __restrict__ nbr,
    const int* __restrict__ cntp,
    const float* __restrict__ w0, const float* __restrict__ b0,
    const float* __restrict__ w1, const float* __restrict__ b1,
    const float* __restrict__ w2, const float* __restrict__ b2,
    float* __restrict__ x1) {
  __shared__ float ins[35];
  __shared__ float h[64];
  const int blk = blockIdx.x;  // B*1024
  const int t = threadIdx.x;
  const int b = blk >> 10;
  const int c = cntp[blk];
  const float cx = pos_s[(size_t)blk * 3 + 0];
  const float cy = pos_s[(size_t)blk * 3 + 1];
  const float cz = pos_s[(size_t)blk * 3 + 2];
  float best = -__builtin_inff();
  for (int r = 0; r < c; ++r) {
    int j = nbr[(size_t)blk * KNB + r];
    if (t < 32) {
      ins[t] = x0[((size_t)(b * N0) + j) * 32 + t];
    } else if (t < 35) {
      float pv = pos[((size_t)(b * N0) + j) * 3 + (t - 32)];
      float cv = (t == 32) ? cx : (t == 33) ? cy : cz;
      ins[t] = pv - cv;
    }
    __syncthreads();
    float v = b0[t];
#pragma unroll
    for (int i = 0; i < 35; ++i) v = fmaf(ins[i], w0[i * 64 + t], v);
    v = fmaxf(v, 0.f);
    h[t] = v;
    __syncthreads();
    float v2 = b1[t];
#pragma unroll
    for (int i = 0; i < 64; ++i) v2 = fmaf(h[i], w1[i * 64 + t], v2);
    v2 = fmaxf(v2, 0.f);
    __syncthreads();
    h[t] = v2;
    __syncthreads();
    float v3 = b2[t];
#pragma unroll
    for (int i = 0; i < 64; ++i) v3 = fmaf(h[i], w2[i * 64 + t], v3);
    best = fmaxf(best, v3);
    __syncthreads();
  }
  x1[(size_t)blk * 64 + t] = best;
}

// ---------------- stage 2 conv: 67 -> 128 -> 128 -> 256, max over nbrs ----------------
__global__ void __launch_bounds__(256) conv2_kernel(
    const float* __restrict__ x1, const float* __restrict__ pos1,
    const float* __restrict__ pos2, const int* __restrict__ nbr,
    const int* __restrict__ cntp,
    const float* __restrict__ w0, const float* __restrict__ b0,
    const float* __restrict__ w1, const float* __restrict__ b1,
    const float* __restrict__ w2, const float* __restrict__ b2,
    float* __restrict__ x2) {
  __shared__ __attribute__((aligned(16))) float msg[64][68];
  __shared__ __attribute__((aligned(16))) float h[64][128];
  __shared__ float red[8][256];
  const int blk = blockIdx.x;  // B*256
  const int t = threadIdx.x;
  const int b = blk >> 8;
  const int c = cntp[blk];
  const float cx = pos2[(size_t)blk * 3 + 0];
  const float cy = pos2[(size_t)blk * 3 + 1];
  const float cz = pos2[(size_t)blk * 3 + 2];
  for (int idx = t; idx < 64 * 68; idx += 256) {
    int r = idx / 68;
    int k = idx - r * 68;
    float v = 0.f;
    if (r < c && k < 67) {
      int j = nbr[(size_t)blk * KNB + r];
      if (k < 64) {
        v = x1[((size_t)(b * 1024) + j) * 64 + k];
      } else {
        float pv = pos1[((size_t)(b * 1024) + j) * 3 + (k - 64)];
        v = pv - ((k == 64) ? cx : (k == 65) ? cy : cz);
      }
    }
    msg[r][k] = v;
  }
  __syncthreads();
  const int rg = t >> 5;  // 8 row-groups of 8 rows
  const int cg = t & 31;
  // L1: K=67 -> h[64][128]
  {
    float acc[8][4] = {};
    for (int i4 = 0; i4 < 16; ++i4) {
      float wv[4][4];
#pragma unroll
      for (int k = 0; k < 4; ++k) {
        float4 q = *(const float4*)&w0[(size_t)(i4 * 4 + k) * 128 + cg * 4];
        wv[k][0] = q.x; wv[k][1] = q.y; wv[k][2] = q.z; wv[k][3] = q.w;
      }
#pragma unroll
      for (int rr = 0; rr < 8; ++rr) {
        float4 aq = *(const float4*)&msg[rg * 8 + rr][i4 * 4];
        float a[4] = {aq.x, aq.y, aq.z, aq.w};
#pragma unroll
        for (int k = 0; k < 4; ++k)
#pragma unroll
          for (int cc = 0; cc < 4; ++cc)
            acc[rr][cc] = fmaf(a[k], wv[k][cc], acc[rr][cc]);
      }
    }
#pragma unroll
    for (int i = 64; i < 67; ++i) {
      float wv[4];
#pragma unroll
      for (int cc = 0; cc < 4; ++cc) wv[cc] = w0[(size_t)i * 128 + cg * 4 + cc];
#pragma unroll
      for (int rr = 0; rr < 8; ++rr) {
        float a = msg[rg * 8 + rr][i];
#pragma unroll
        for (int cc = 0; cc < 4; ++cc) acc[rr][cc] = fmaf(a, wv[cc], acc[rr][cc]);
      }
    }
#pragma unroll
    for (int rr = 0; rr < 8; ++rr)
#pragma unroll
      for (int cc = 0; cc < 4; ++cc)
        h[rg * 8 + rr][cg * 4 + cc] = fmaxf(acc[rr][cc] + b0[cg * 4 + cc], 0.f);
  }
  __syncthreads();
  // L2: K=128, in-place on h
  {
    float acc[8][4] = {};
    for (int i4 = 0; i4 < 32; ++i4) {
      float wv[4][4];
#pragma unroll
      for (int k = 0; k < 4; ++k) {
        float4 q = *(const float4*)&w1[(size_t)(i4 * 4 + k) * 128 + cg * 4];
        wv[k][0] = q.x; wv[k][1] = q.y; wv[k][2] = q.z; wv[k][3] = q.w;
      }
#pragma unroll
      for (int rr = 0; rr < 8; ++rr) {
        float4 aq = *(const float4*)&h[rg * 8 + rr][i4 * 4];
        float a[4] = {aq.x, aq.y, aq.z, aq.w};
#pragma unroll
        for (int k = 0; k < 4; ++k)
#pragma unroll
          for (int cc = 0; cc < 4; ++cc)
            acc[rr][cc] = fmaf(a[k], wv[k][cc], acc[rr][cc]);
      }
    }
    __syncthreads();  // all reads of h done before overwrite
#pragma unroll
    for (int rr = 0; rr < 8; ++rr)
#pragma unroll
      for (int cc = 0; cc < 4; ++cc)
        h[rg * 8 + rr][cg * 4 + cc] = fmaxf(acc[rr][cc] + b1[cg * 4 + cc], 0.f);
  }
  __syncthreads();
  // L3: K=128 -> 64x256, then masked max over rows
  {
    float acc[8][8] = {};
    for (int i4 = 0; i4 < 32; ++i4) {
      float wv[4][8];
#pragma unroll
      for (int k = 0; k < 4; ++k) {
        float4 q0 = *(const float4*)&w2[(size_t)(i4 * 4 + k) * 256 + cg * 8];
        float4 q1 = *(const float4*)&w2[(size_t)(i4 * 4 + k) * 256 + cg * 8 + 4];
        wv[k][0] = q0.x; wv[k][1] = q0.y; wv[k][2] = q0.z; wv[k][3] = q0.w;
        wv[k][4] = q1.x; wv[k][5] = q1.y; wv[k][6] = q1.z; wv[k][7] = q1.w;
      }
#pragma unroll
      for (int rr = 0; rr < 8; ++rr) {
        float4 aq = *(const float4*)&h[rg * 8 + rr][i4 * 4];
        float a[4] = {aq.x, aq.y, aq.z, aq.w};
#pragma unroll
        for (int k = 0; k < 4; ++k)
#pragma unroll
          for (int cc = 0; cc < 8; ++cc)
            acc[rr][cc] = fmaf(a[k], wv[k][cc], acc[rr][cc]);
      }
    }
    float mx[8];
#pragma unroll
    for (int cc = 0; cc < 8; ++cc) mx[cc] = -__builtin_inff();
#pragma unroll
    for (int rr = 0; rr < 8; ++rr) {
      if (rg * 8 + rr < c) {
#pragma unroll
        for (int cc = 0; cc < 8; ++cc)
          mx[cc] = fmaxf(mx[cc], acc[rr][cc] + b2[cg * 8 + cc]);
      }
    }
#pragma unroll
    for (int cc = 0; cc < 8; ++cc) red[rg][cg * 8 + cc] = mx[cc];
  }
  __syncthreads();
  {
    float v = red[0][t];
#pragma unroll
    for (int g = 1; g < 8; ++g) v = fmaxf(v, red[g][t]);
    x2[(size_t)blk * 256 + t] = v;
  }
}

// ---------------- stage 3 conv: 259 -> 256 -> 512 -> 512, max over nbrs ----------------
__global__ void __launch_bounds__(256) conv3_kernel(
    const float* __restrict__ x2, const float* __restrict__ pos2,
    const float* __restrict__ pos3, const int* __restrict__ nbr,
    const int* __restrict__ cntp,
    const float* __restrict__ w0, const float* __restrict__ b0,
    const float* __restrict__ w1, const float* __restrict__ b1,
    const float* __restrict__ w2, const float* __restrict__ b2,
    float* __restrict__ out) {
  __shared__ __attribute__((aligned(16))) float msg[16][260];
  __shared__ __attribute__((aligned(16))) float h[16][512];
  __shared__ float red[4][512];
  __shared__ float omax[512];
  const int blk = blockIdx.x;  // B*64
  const int t = threadIdx.x;
  const int b = blk >> 6;
  const int c = cntp[blk];
  const float cx = pos3[(size_t)blk * 3 + 0];
  const float cy = pos3[(size_t)blk * 3 + 1];
  const float cz = pos3[(size_t)blk * 3 + 2];
  omax[t] = -__builtin_inff();
  omax[t + 256] = -__builtin_inff();
  const int rg = t >> 6;  // 4 row-groups of 4 rows
  const int cg = t & 63;
  __syncthreads();
  for (int ch = 0; ch < 4; ++ch) {
    if (ch * 16 >= c) break;
    for (int idx = t; idx < 16 * 260; idx += 256) {
      int r = idx / 260;
      int k = idx - r * 260;
      int rglob = ch * 16 + r;
      float v = 0.f;
      if (rglob < c && k < 259) {
        int j = nbr[(size_t)blk * KNB + rglob];
        if (k < 256) {
          v = x2[((size_t)(b * 256) + j) * 256 + k];
        } else {
          float pv = pos2[((size_t)(b * 256) + j) * 3 + (k - 256)];
          v = pv - ((k == 256) ? cx : (k == 257) ? cy : cz);
        }
      }
      msg[r][k] = v;
    }
    __syncthreads();
    // L1: 16x256, K=259
    {
      float acc[4][4] = {};
      for (int i4 = 0; i4 < 64; ++i4) {
        float wv[4][4];
#pragma unroll
        for (int k = 0; k < 4; ++k) {
          float4 q = *(const float4*)&w0[(size_t)(i4 * 4 + k) * 256 + cg * 4];
          wv[k][0] = q.x; wv[k][1] = q.y; wv[k][2] = q.z; wv[k][3] = q.w;
        }
#pragma unroll
        for (int rr = 0; rr < 4; ++rr) {
          float4 aq = *(const float4*)&msg[rg * 4 + rr][i4 * 4];
          float a[4] = {aq.x, aq.y, aq.z, aq.w};
#pragma unroll
          for (int k = 0; k < 4; ++k)
#pragma unroll
            for (int cc = 0; cc < 4; ++cc)
              acc[rr][cc] = fmaf(a[k], wv[k][cc], acc[rr][cc]);
        }
      }
#pragma unroll
      for (int i = 256; i < 259; ++i) {
        float wv[4];
#pragma unroll
        for (int cc = 0; cc < 4; ++cc) wv[cc] = w0[(size_t)i * 256 + cg * 4 + cc];
#pragma unroll
        for (int rr = 0; rr < 4; ++rr) {
          float a = msg[rg * 4 + rr][i];
#pragma unroll
          for (int cc = 0; cc < 4; ++cc) acc[rr][cc] = fmaf(a, wv[cc], acc[rr][cc]);
        }
      }
#pragma unroll
      for (int rr = 0; rr < 4; ++rr)
#pragma unroll
        for (int cc = 0; cc < 4; ++cc)
          h[rg * 4 + rr][cg * 4 + cc] = fmaxf(acc[rr][cc] + b0[cg * 4 + cc], 0.f);
    }
    __syncthreads();
    // L2: 16x512, K=256, in-place on h (read cols 0..255, write 0..511)
    {
      float acc[4][8] = {};
      for (int i4 = 0; i4 < 64; ++i4) {
        float wv[4][8];
#pragma unroll
        for (int k = 0; k < 4; ++k) {
          float4 q0 = *(const float4*)&w1[(size_t)(i4 * 4 + k) * 512 + cg * 8];
          float4 q1 = *(const float4*)&w1[(size_t)(i4 * 4 + k) * 512 + cg * 8 + 4];
          wv[k][0] = q0.x; wv[k][1] = q0.y; wv[k][2] = q0.z; wv[k][3] = q0.w;
          wv[k][4] = q1.x; wv[k][5] = q1.y; wv[k][6] = q1.z; wv[k][7] = q1.w;
        }
#pragma unroll
        for (int rr = 0; rr < 4; ++rr) {
          float4 aq = *(const float4*)&h[rg * 4 + rr][i4 * 4];
          float a[4] = {aq.x, aq.y, aq.z, aq.w};
#pragma unroll
          for (int k = 0; k < 4; ++k)
#pragma unroll
            for (int cc = 0; cc < 8; ++cc)
              acc[rr][cc] = fmaf(a[k], wv[k][cc], acc[rr][cc]);
        }
      }
      __syncthreads();
#pragma unroll
      for (int rr = 0; rr < 4; ++rr)
#pragma unroll
        for (int cc = 0; cc < 8; ++cc)
          h[rg * 4 + rr][cg * 8 + cc] = fmaxf(acc[rr][cc] + b1[cg * 8 + cc], 0.f);
    }
    __syncthreads();
    // L3: 16x512, K=512, masked max
    {
      float acc[4][8] = {};
      for (int i4 = 0; i4 < 128; ++i4) {
        float wv[4][8];
#pragma unroll
        for (int k = 0; k < 4; ++k) {
          float4 q0 = *(const float4*)&w2[(size_t)(i4 * 4 + k) * 512 + cg * 8];
          float4 q1 = *(const float4*)&w2[(size_t)(i4 * 4 + k) * 512 + cg * 8 + 4];
          wv[k][0] = q0.x; wv[k][1] = q0.y; wv[k][2] = q0.z; wv[k][3] = q0.w;
          wv[k][4] = q1.x; wv[k][5] = q1.y; wv[k][6] = q1.z; wv[k][7] = q1.w;
        }
#pragma unroll
        for (int rr = 0; rr < 4; ++rr) {
          float4 aq = *(const float4*)&h[rg * 4 + rr][i4 * 4];
          float a[4] = {aq.x, aq.y, aq.z, aq.w};
#pragma unroll
          for (int k = 0; k < 4; ++k)
#pragma unroll
            for (int cc = 0; cc < 8; ++cc)
              acc[rr][cc] = fmaf(a[k], wv[k][cc], acc[rr][cc]);
        }
      }
      float mx[8];
#pragma unroll
      for (int cc = 0; cc < 8; ++cc) mx[cc] = -__builtin_inff();
#pragma unroll
      for (int rr = 0; rr < 4; ++rr) {
        if (ch * 16 + rg * 4 + rr < c) {
#pragma unroll
          for (int cc = 0; cc < 8; ++cc)
            mx[cc] = fmaxf(mx[cc], acc[rr][cc] + b2[cg * 8 + cc]);
        }
      }
#pragma unroll
      for (int cc = 0; cc < 8; ++cc) red[rg][cg * 8 + cc] = mx[cc];
    }
    __syncthreads();
    for (int k = t; k < 512; k += 256) {
      float v = omax[k];
#pragma unroll
      for (int g = 0; g < 4; ++g) v = fmaxf(v, red[g][k]);
      omax[k] = v;
    }
    __syncthreads();
  }
  out[(size_t)blk * 512 + t] = omax[t];
  out[(size_t)blk * 512 + t + 256] = omax[t + 256];
}

extern "C" void kernel_launch(void* const* d_in, const int* in_sizes, int n_in,
                              void* d_out, int out_size, void* d_ws, size_t ws_size,
                              hipStream_t stream) {
  const int* feat = (const int*)d_in[0];
  const float* pos = (const float*)d_in[1];
  const float* emb = (const float*)d_in[2];
  const float* pid = (const float*)d_in[3];
  const float* s1w0 = (const float*)d_in[4];
  const float* s1b0 = (const float*)d_in[5];
  const float* s1w1 = (const float*)d_in[6];
  const float* s1b1 = (const float*)d_in[7];
  const float* s1w2 = (const float*)d_in[8];
  const float* s1b2 = (const float*)d_in[9];
  const float* s2w0 = (const float*)d_in[10];
  const float* s2b0 = (const float*)d_in[11];
  const float* s2w1 = (const float*)d_in[12];
  const float* s2b1 = (const float*)d_in[13];
  const float* s2w2 = (const float*)d_in[14];
  const float* s2b2 = (const float*)d_in[15];
  const float* s3w0 = (const float*)d_in[16];
  const float* s3b0 = (const float*)d_in[17];
  const float* s3w1 = (const float*)d_in[18];
  const float* s3b1 = (const float*)d_in[19];
  const float* s3w2 = (const float*)d_in[20];
  const float* s3b2 = (const float*)d_in[21];
  (void)in_sizes; (void)n_in; (void)out_size; (void)ws_size;

  char* ws = (char*)d_ws;
  size_t off = 0;
  auto alloc = [&](size_t nbytes) {
    void* p = ws + off;
    off = (off + nbytes + 255) & ~(size_t)255;
    return p;
  };
  float* x0 = (float*)alloc((size_t)B * N0 * 32 * 4);
  int* idx1 = (int*)alloc((size_t)B * 1024 * 4);
  float* pos1 = (float*)alloc((size_t)B * 1024 * 3 * 4);
  int* nbr1 = (int*)alloc((size_t)B * 1024 * KNB * 4);
  int* cnt1 = (int*)alloc((size_t)B * 1024 * 4);
  float* x1 = (float*)alloc((size_t)B * 1024 * 64 * 4);
  int* idx2 = (int*)alloc((size_t)B * 256 * 4);
  float* pos2 = (float*)alloc((size_t)B * 256 * 3 * 4);
  int* nbr2 = (int*)alloc((size_t)B * 256 * KNB * 4);
  int* cnt2 = (int*)alloc((size_t)B * 256 * 4);
  float* x2 = (float*)alloc((size_t)B * 256 * 256 * 4);
  int* idx3 = (int*)alloc((size_t)B * 64 * 4);
  int* nbr3 = (int*)alloc((size_t)B * 64 * KNB * 4);
  int* cnt3 = (int*)alloc((size_t)B * 64 * 4);

  float* xout = (float*)d_out;                 // (B,64,512)
  float* pos3 = xout + (size_t)B * 64 * 512;   // (B,64,3)

  const float r2a = (float)(0.05 * 0.05);
  const float r2b = (float)(0.3 * 0.3);
  const float r2c = (float)(0.5 * 0.5);

  x0_kernel<<<(B * N0 * 32 + 255) / 256, 256, 0, stream>>>(feat, emb, pid, x0);

  fps_kernel<4096, 1024, 512><<<B, 512, 0, stream>>>(pos, idx1, pos1);
  radius_kernel<4096, 1024><<<B * 1024, 256, 0, stream>>>(pos, pos1, r2a, nbr1, cnt1);
  conv1_kernel<<<B * 1024, 64, 0, stream>>>(x0, pos, pos1, nbr1, cnt1,
                                            s1w0, s1b0, s1w1, s1b1, s1w2, s1b2, x1);

  fps_kernel<1024, 256, 256><<<B, 256, 0, stream>>>(pos1, idx2, pos2);
  radius_kernel<1024, 256><<<B * 256, 256, 0, stream>>>(pos1, pos2, r2b, nbr2, cnt2);
  conv2_kernel<<<B * 256, 256, 0, stream>>>(x1, pos1, pos2, nbr2, cnt2,
                                            s2w0, s2b0, s2w1, s2b1, s2w2, s2b2, x2);

  fps_kernel<256, 64, 256><<<B, 256, 0, stream>>>(pos2, idx3, pos3);
  radius_kernel<256, 64><<<B * 64, 256, 0, stream>>>(pos2, pos3, r2c, nbr3, cnt3);
  conv3_kernel<<<B * 64, 256, 0, stream>>>(x2, pos2, pos3, nbr3, cnt3,
                                           s3w0, s3b0, s3w1, s3b1, s3w2, s3b2, xout);
}

// Round 2
// 1881.068 us; speedup vs baseline: 1.0619x; 1.0619x over previous
//
#include <hip/hip_runtime.h>

#define DEVI static __device__ __forceinline__

constexpr int B = 8;
constexpr int N0 = 4096;
constexpr int KNB = 64;

// d2 exactly as numpy: ((dx*dx + dy*dy) + dz*dz), no FMA contraction.
DEVI float dist2f(float ax, float ay, float az, float bx, float by, float bz) {
#pragma clang fp contract(off)
  float dx = ax - bx;
  float dy = ay - by;
  float dz = az - bz;
  return (dx * dx + dy * dy) + dz * dz;
}

// argmin key: min d wins, ties -> lowest index
DEVI unsigned long long packMinKey(float v, int i) {
  return ((unsigned long long)__float_as_uint(v) << 32) | (unsigned int)i;
}
DEVI unsigned long long shflXorU64(unsigned long long v, int m) {
  unsigned int lo = (unsigned int)v;
  unsigned int hi = (unsigned int)(v >> 32);
  lo = __shfl_xor(lo, m, 64);
  hi = __shfl_xor(hi, m, 64);
  return ((unsigned long long)hi << 32) | lo;
}

// ---------------- embedding + point_id_emb ----------------
__global__ void __launch_bounds__(256) x0_kernel(const int* __restrict__ feat,
                                                 const float* __restrict__ emb,
                                                 const float* __restrict__ pid,
                                                 float* __restrict__ x0) {
  int gid = blockIdx.x * 256 + threadIdx.x;  // over B*N0*32
  if (gid >= B * N0 * 32) return;
  int c = gid & 31;
  int bn = gid >> 5;
  int n = bn & (N0 - 1);
  int f = feat[bn];
  float v = emb[f * 32 + c];
  if (n < 1024) v += pid[n * 32 + c];
  x0[gid] = v;
}

// ---------------- farthest point sampling (latency-optimized) ----------------
// Per iteration: register best-tracking -> 6-level u64 shuffle argmax ->
// (cross-wave via LDS, 1 barrier, double-buffered) -> selected pos from LDS
// float4 table (one ds_read_b128) -> distance update.
// Selection semantics identical to jnp.argmax (ties -> lowest index).
template <int NPTS, int M, int BLK>
__global__ void __launch_bounds__(BLK) fps_kernel(const float* __restrict__ pos,
                                                  float* __restrict__ pos_out) {
  constexpr int EPT = NPTS / BLK;
  constexpr int NW = BLK / 64;
  __shared__ float4 posl[NPTS];
  __shared__ unsigned long long red[2][NW < 2 ? 2 : NW];
  const int b = blockIdx.x;
  const int t = threadIdx.x;
  const float* pb = pos + (size_t)b * NPTS * 3;
  float px[EPT], py[EPT], pz[EPT], d[EPT];
#pragma unroll
  for (int e = 0; e < EPT; ++e) {
    int i = t + e * BLK;
    float x = pb[i * 3 + 0];
    float y = pb[i * 3 + 1];
    float z = pb[i * 3 + 2];
    px[e] = x; py[e] = y; pz[e] = z;
    posl[i] = make_float4(x, y, z, 0.f);
  }
  float sx = pb[0], sy = pb[1], sz = pb[2];
  if (t == 0) {
    pos_out[(size_t)(b * M) * 3 + 0] = sx;
    pos_out[(size_t)(b * M) * 3 + 1] = sy;
    pos_out[(size_t)(b * M) * 3 + 2] = sz;
  }
  float bestv = -1.f;  // all d2 >= 0
  int bestidx = 0;
#pragma unroll
  for (int e = 0; e < EPT; ++e) {
    float v = dist2f(px[e], py[e], pz[e], sx, sy, sz);
    d[e] = v;
    if (v > bestv) { bestv = v; bestidx = t + e * BLK; }  // strict > keeps lowest idx in-lane
  }
  for (int it = 1; it < M; ++it) {
    // pack: max d wins; ties -> lowest index via inverted low word
    unsigned long long k =
        ((unsigned long long)__float_as_uint(bestv) << 32) |
        (unsigned int)(0x7fffffff - bestidx);
#pragma unroll
    for (int off = 32; off > 0; off >>= 1) {
      unsigned long long o = shflXorU64(k, off);
      k = (k > o) ? k : o;
    }
    if constexpr (NW > 1) {
      if ((t & 63) == 0) red[it & 1][t >> 6] = k;
      __syncthreads();
#pragma unroll
      for (int w = 0; w < NW; ++w) {
        unsigned long long o = red[it & 1][w];
        k = (k > o) ? k : o;
      }
    }
    const int sel = 0x7fffffff - (int)(unsigned int)(k & 0xffffffffULL);
    float4 sp = posl[sel];  // LDS broadcast, ~120cy vs ~300+ global
    if (t == 0) {
      pos_out[(size_t)(b * M + it) * 3 + 0] = sp.x;
      pos_out[(size_t)(b * M + it) * 3 + 1] = sp.y;
      pos_out[(size_t)(b * M + it) * 3 + 2] = sp.z;
    }
    bestv = -1.f;
    bestidx = 0;
#pragma unroll
    for (int e = 0; e < EPT; ++e) {
      float nd = dist2f(px[e], py[e], pz[e], sp.x, sp.y, sp.z);
      float v = fminf(d[e], nd);
      d[e] = v;
      if (v > bestv) { bestv = v; bestidx = t + e * BLK; }
    }
  }
}

// ---------------- radius neighbors (<=64 nearest within r) ----------------
template <int NPTS, int M>
__global__ void __launch_bounds__(256) radius_kernel(const float* __restrict__ pos,
                                                     const float* __restrict__ pos_s,
                                                     float r2,
                                                     int* __restrict__ nbr,
                                                     int* __restrict__ cnt) {
  __shared__ float d2s[NPTS];
  __shared__ unsigned long long red[4];
  __shared__ int ctr;
  const float INFV = __builtin_inff();
  const int blk = blockIdx.x;
  const int t = threadIdx.x;
  const int b = blk / M;
  const float* pb = pos + (size_t)b * NPTS * 3;
  const float cx = pos_s[(size_t)blk * 3 + 0];
  const float cy = pos_s[(size_t)blk * 3 + 1];
  const float cz = pos_s[(size_t)blk * 3 + 2];
  if (t == 0) ctr = 0;
  __syncthreads();
  for (int j = t; j < NPTS; j += 256) {
    float d2 = dist2f(pb[j * 3 + 0], pb[j * 3 + 1], pb[j * 3 + 2], cx, cy, cz);
    d2s[j] = (d2 <= r2) ? d2 : INFV;
  }
  __syncthreads();
  for (int j = t; j < NPTS; j += 256) {
    if (d2s[j] < INFV) {
      int p = atomicAdd(&ctr, 1);
      if (p < KNB) nbr[(size_t)blk * KNB + p] = j;
    }
  }
  __syncthreads();
  const int c = ctr;
  if (c <= KNB) {
    if (t == 0) cnt[blk] = c;
    return;
  }
  // overflow: exact 64-nearest, ties -> lower index (matches lax.top_k)
  for (int k = 0; k < KNB; ++k) {
    unsigned long long lk = ~0ULL;
    for (int j = t; j < NPTS; j += 256) {
      unsigned long long kk = packMinKey(d2s[j], j);
      lk = (lk < kk) ? lk : kk;
    }
#pragma unroll
    for (int off = 32; off > 0; off >>= 1) {
      unsigned long long o = shflXorU64(lk, off);
      lk = (lk < o) ? lk : o;
    }
    if ((t & 63) == 0) red[t >> 6] = lk;
    __syncthreads();
    lk = red[0];
#pragma unroll
    for (int w = 1; w < 4; ++w) {
      unsigned long long o = red[w];
      lk = (lk < o) ? lk : o;
    }
    int idx = (int)(unsigned int)(lk & 0xffffffffULL);
    if (t == 0) {
      nbr[(size_t)blk * KNB + k] = idx;
      d2s[idx] = INFV;
    }
    __syncthreads();
  }
  if (t == 0) cnt[blk] = KNB;
}

// ---------------- stage 1 conv: 35 -> 64 -> 64 -> 64, max over nbrs ----------------
__global__ void __launch_bounds__(64) conv1_kernel(
    const float* __restrict__ x0, const float* __restrict__ pos,
    const float* __restrict__ pos_s, const int* __restrict__ nbr,
    const int* __restrict__ cntp,
    const float* __restrict__ w0, const float* __restrict__ b0,
    const float* __restrict__ w1, const float* __restrict__ b1,
    const float* __restrict__ w2, const float* __restrict__ b2,
    float* __restrict__ x1) {
  __shared__ float ins[35];
  __shared__ float h[64];
  const int blk = blockIdx.x;  // B*1024
  const int t = threadIdx.x;
  const int b = blk >> 10;
  const int c = cntp[blk];
  const float cx = pos_s[(size_t)blk * 3 + 0];
  const float cy = pos_s[(size_t)blk * 3 + 1];
  const float cz = pos_s[(size_t)blk * 3 + 2];
  float best = -__builtin_inff();
  for (int r = 0; r < c; ++r) {
    int j = nbr[(size_t)blk * KNB + r];
    if (t < 32) {
      ins[t] = x0[((size_t)(b * N0) + j) * 32 + t];
    } else if (t < 35) {
      float pv = pos[((size_t)(b * N0) + j) * 3 + (t - 32)];
      float cv = (t == 32) ? cx : (t == 33) ? cy : cz;
      ins[t] = pv - cv;
    }
    __syncthreads();
    float v = b0[t];
#pragma unroll
    for (int i = 0; i < 35; ++i) v = fmaf(ins[i], w0[i * 64 + t], v);
    v = fmaxf(v, 0.f);
    h[t] = v;
    __syncthreads();
    float v2 = b1[t];
#pragma unroll
    for (int i = 0; i < 64; ++i) v2 = fmaf(h[i], w1[i * 64 + t], v2);
    v2 = fmaxf(v2, 0.f);
    __syncthreads();
    h[t] = v2;
    __syncthreads();
    float v3 = b2[t];
#pragma unroll
    for (int i = 0; i < 64; ++i) v3 = fmaf(h[i], w2[i * 64 + t], v3);
    best = fmaxf(best, v3);
    __syncthreads();
  }
  x1[(size_t)blk * 64 + t] = best;
}

// ---------------- stage 2 conv: 67 -> 128 -> 128 -> 256, max over nbrs ----------------
__global__ void __launch_bounds__(256) conv2_kernel(
    const float* __restrict__ x1, const float* __restrict__ pos1,
    const float* __restrict__ pos2, const int* __restrict__ nbr,
    const int* __restrict__ cntp,
    const float* __restrict__ w0, const float* __restrict__ b0,
    const float* __restrict__ w1, const float* __restrict__ b1,
    const float* __restrict__ w2, const float* __restrict__ b2,
    float* __restrict__ x2) {
  __shared__ __attribute__((aligned(16))) float msg[64][68];
  __shared__ __attribute__((aligned(16))) float h[64][128];
  __shared__ float red[8][256];
  const int blk = blockIdx.x;  // B*256
  const int t = threadIdx.x;
  const int b = blk >> 8;
  const int c = cntp[blk];
  const float cx = pos2[(size_t)blk * 3 + 0];
  const float cy = pos2[(size_t)blk * 3 + 1];
  const float cz = pos2[(size_t)blk * 3 + 2];
  for (int idx = t; idx < 64 * 68; idx += 256) {
    int r = idx / 68;
    int k = idx - r * 68;
    float v = 0.f;
    if (r < c && k < 67) {
      int j = nbr[(size_t)blk * KNB + r];
      if (k < 64) {
        v = x1[((size_t)(b * 1024) + j) * 64 + k];
      } else {
        float pv = pos1[((size_t)(b * 1024) + j) * 3 + (k - 64)];
        v = pv - ((k == 64) ? cx : (k == 65) ? cy : cz);
      }
    }
    msg[r][k] = v;
  }
  __syncthreads();
  const int rg = t >> 5;  // 8 row-groups of 8 rows
  const int cg = t & 31;
  // L1: K=67 -> h[64][128]
  {
    float acc[8][4] = {};
    for (int i4 = 0; i4 < 16; ++i4) {
      float wv[4][4];
#pragma unroll
      for (int k = 0; k < 4; ++k) {
        float4 q = *(const float4*)&w0[(size_t)(i4 * 4 + k) * 128 + cg * 4];
        wv[k][0] = q.x; wv[k][1] = q.y; wv[k][2] = q.z; wv[k][3] = q.w;
      }
#pragma unroll
      for (int rr = 0; rr < 8; ++rr) {
        float4 aq = *(const float4*)&msg[rg * 8 + rr][i4 * 4];
        float a[4] = {aq.x, aq.y, aq.z, aq.w};
#pragma unroll
        for (int k = 0; k < 4; ++k)
#pragma unroll
          for (int cc = 0; cc < 4; ++cc)
            acc[rr][cc] = fmaf(a[k], wv[k][cc], acc[rr][cc]);
      }
    }
#pragma unroll
    for (int i = 64; i < 67; ++i) {
      float wv[4];
#pragma unroll
      for (int cc = 0; cc < 4; ++cc) wv[cc] = w0[(size_t)i * 128 + cg * 4 + cc];
#pragma unroll
      for (int rr = 0; rr < 8; ++rr) {
        float a = msg[rg * 8 + rr][i];
#pragma unroll
        for (int cc = 0; cc < 4; ++cc) acc[rr][cc] = fmaf(a, wv[cc], acc[rr][cc]);
      }
    }
#pragma unroll
    for (int rr = 0; rr < 8; ++rr)
#pragma unroll
      for (int cc = 0; cc < 4; ++cc)
        h[rg * 8 + rr][cg * 4 + cc] = fmaxf(acc[rr][cc] + b0[cg * 4 + cc], 0.f);
  }
  __syncthreads();
  // L2: K=128, in-place on h
  {
    float acc[8][4] = {};
    for (int i4 = 0; i4 < 32; ++i4) {
      float wv[4][4];
#pragma unroll
      for (int k = 0; k < 4; ++k) {
        float4 q = *(const float4*)&w1[(size_t)(i4 * 4 + k) * 128 + cg * 4];
        wv[k][0] = q.x; wv[k][1] = q.y; wv[k][2] = q.z; wv[k][3] = q.w;
      }
#pragma unroll
      for (int rr = 0; rr < 8; ++rr) {
        float4 aq = *(const float4*)&h[rg * 8 + rr][i4 * 4];
        float a[4] = {aq.x, aq.y, aq.z, aq.w};
#pragma unroll
        for (int k = 0; k < 4; ++k)
#pragma unroll
          for (int cc = 0; cc < 4; ++cc)
            acc[rr][cc] = fmaf(a[k], wv[k][cc], acc[rr][cc]);
      }
    }
    __syncthreads();  // all reads of h done before overwrite
#pragma unroll
    for (int rr = 0; rr < 8; ++rr)
#pragma unroll
      for (int cc = 0; cc < 4; ++cc)
        h[rg * 8 + rr][cg * 4 + cc] = fmaxf(acc[rr][cc] + b1[cg * 4 + cc], 0.f);
  }
  __syncthreads();
  // L3: K=128 -> 64x256, then masked max over rows
  {
    float acc[8][8] = {};
    for (int i4 = 0; i4 < 32; ++i4) {
      float wv[4][8];
#pragma unroll
      for (int k = 0; k < 4; ++k) {
        float4 q0 = *(const float4*)&w2[(size_t)(i4 * 4 + k) * 256 + cg * 8];
        float4 q1 = *(const float4*)&w2[(size_t)(i4 * 4 + k) * 256 + cg * 8 + 4];
        wv[k][0] = q0.x; wv[k][1] = q0.y; wv[k][2] = q0.z; wv[k][3] = q0.w;
        wv[k][4] = q1.x; wv[k][5] = q1.y; wv[k][6] = q1.z; wv[k][7] = q1.w;
      }
#pragma unroll
      for (int rr = 0; rr < 8; ++rr) {
        float4 aq = *(const float4*)&h[rg * 8 + rr][i4 * 4];
        float a[4] = {aq.x, aq.y, aq.z, aq.w};
#pragma unroll
        for (int k = 0; k < 4; ++k)
#pragma unroll
          for (int cc = 0; cc < 8; ++cc)
            acc[rr][cc] = fmaf(a[k], wv[k][cc], acc[rr][cc]);
      }
    }
    float mx[8];
#pragma unroll
    for (int cc = 0; cc < 8; ++cc) mx[cc] = -__builtin_inff();
#pragma unroll
    for (int rr = 0; rr < 8; ++rr) {
      if (rg * 8 + rr < c) {
#pragma unroll
        for (int cc = 0; cc < 8; ++cc)
          mx[cc] = fmaxf(mx[cc], acc[rr][cc] + b2[cg * 8 + cc]);
      }
    }
#pragma unroll
    for (int cc = 0; cc < 8; ++cc) red[rg][cg * 8 + cc] = mx[cc];
  }
  __syncthreads();
  {
    float v = red[0][t];
#pragma unroll
    for (int g = 1; g < 8; ++g) v = fmaxf(v, red[g][t]);
    x2[(size_t)blk * 256 + t] = v;
  }
}

// ---------------- stage 3 conv: 259 -> 256 -> 512 -> 512, max over nbrs ----------------
__global__ void __launch_bounds__(256) conv3_kernel(
    const float* __restrict__ x2, const float* __restrict__ pos2,
    const float* __restrict__ pos3, const int* __restrict__ nbr,
    const int* __restrict__ cntp,
    const float* __restrict__ w0, const float* __restrict__ b0,
    const float* __restrict__ w1, const float* __restrict__ b1,
    const float* __restrict__ w2, const float* __restrict__ b2,
    float* __restrict__ out) {
  __shared__ __attribute__((aligned(16))) float msg[16][260];
  __shared__ __attribute__((aligned(16))) float h[16][512];
  __shared__ float red[4][512];
  __shared__ float omax[512];
  const int blk = blockIdx.x;  // B*64
  const int t = threadIdx.x;
  const int b = blk >> 6;
  const int c = cntp[blk];
  const float cx = pos3[(size_t)blk * 3 + 0];
  const float cy = pos3[(size_t)blk * 3 + 1];
  const float cz = pos3[(size_t)blk * 3 + 2];
  omax[t] = -__builtin_inff();
  omax[t + 256] = -__builtin_inff();
  const int rg = t >> 6;  // 4 row-groups of 4 rows
  const int cg = t & 63;
  __syncthreads();
  for (int ch = 0; ch < 4; ++ch) {
    if (ch * 16 >= c) break;
    for (int idx = t; idx < 16 * 260; idx += 256) {
      int r = idx / 260;
      int k = idx - r * 260;
      int rglob = ch * 16 + r;
      float v = 0.f;
      if (rglob < c && k < 259) {
        int j = nbr[(size_t)blk * KNB + rglob];
        if (k < 256) {
          v = x2[((size_t)(b * 256) + j) * 256 + k];
        } else {
          float pv = pos2[((size_t)(b * 256) + j) * 3 + (k - 256)];
          v = pv - ((k == 256) ? cx : (k == 257) ? cy : cz);
        }
      }
      msg[r][k] = v;
    }
    __syncthreads();
    // L1: 16x256, K=259
    {
      float acc[4][4] = {};
      for (int i4 = 0; i4 < 64; ++i4) {
        float wv[4][4];
#pragma unroll
        for (int k = 0; k < 4; ++k) {
          float4 q = *(const float4*)&w0[(size_t)(i4 * 4 + k) * 256 + cg * 4];
          wv[k][0] = q.x; wv[k][1] = q.y; wv[k][2] = q.z; wv[k][3] = q.w;
        }
#pragma unroll
        for (int rr = 0; rr < 4; ++rr) {
          float4 aq = *(const float4*)&msg[rg * 4 + rr][i4 * 4];
          float a[4] = {aq.x, aq.y, aq.z, aq.w};
#pragma unroll
          for (int k = 0; k < 4; ++k)
#pragma unroll
            for (int cc = 0; cc < 4; ++cc)
              acc[rr][cc] = fmaf(a[k], wv[k][cc], acc[rr][cc]);
        }
      }
#pragma unroll
      for (int i = 256; i < 259; ++i) {
        float wv[4];
#pragma unroll
        for (int cc = 0; cc < 4; ++cc) wv[cc] = w0[(size_t)i * 256 + cg * 4 + cc];
#pragma unroll
        for (int rr = 0; rr < 4; ++rr) {
          float a = msg[rg * 4 + rr][i];
#pragma unroll
          for (int cc = 0; cc < 4; ++cc) acc[rr][cc] = fmaf(a, wv[cc], acc[rr][cc]);
        }
      }
#pragma unroll
      for (int rr = 0; rr < 4; ++rr)
#pragma unroll
        for (int cc = 0; cc < 4; ++cc)
          h[rg * 4 + rr][cg * 4 + cc] = fmaxf(acc[rr][cc] + b0[cg * 4 + cc], 0.f);
    }
    __syncthreads();
    // L2: 16x512, K=256, in-place on h (read cols 0..255, write 0..511)
    {
      float acc[4][8] = {};
      for (int i4 = 0; i4 < 64; ++i4) {
        float wv[4][8];
#pragma unroll
        for (int k = 0; k < 4; ++k) {
          float4 q0 = *(const float4*)&w1[(size_t)(i4 * 4 + k) * 512 + cg * 8];
          float4 q1 = *(const float4*)&w1[(size_t)(i4 * 4 + k) * 512 + cg * 8 + 4];
          wv[k][0] = q0.x; wv[k][1] = q0.y; wv[k][2] = q0.z; wv[k][3] = q0.w;
          wv[k][4] = q1.x; wv[k][5] = q1.y; wv[k][6] = q1.z; wv[k][7] = q1.w;
        }
#pragma unroll
        for (int rr = 0; rr < 4; ++rr) {
          float4 aq = *(const float4*)&h[rg * 4 + rr][i4 * 4];
          float a[4] = {aq.x, aq.y, aq.z, aq.w};
#pragma unroll
          for (int k = 0; k < 4; ++k)
#pragma unroll
            for (int cc = 0; cc < 8; ++cc)
              acc[rr][cc] = fmaf(a[k], wv[k][cc], acc[rr][cc]);
        }
      }
      __syncthreads();
#pragma unroll
      for (int rr = 0; rr < 4; ++rr)
#pragma unroll
        for (int cc = 0; cc < 8; ++cc)
          h[rg * 4 + rr][cg * 8 + cc] = fmaxf(acc[rr][cc] + b1[cg * 8 + cc], 0.f);
    }
    __syncthreads();
    // L3: 16x512, K=512, masked max
    {
      float acc[4][8] = {};
      for (int i4 = 0; i4 < 128; ++i4) {
        float wv[4][8];
#pragma unroll
        for (int k = 0; k < 4; ++k) {
          float4 q0 = *(const float4*)&w2[(size_t)(i4 * 4 + k) * 512 + cg * 8];
          float4 q1 = *(const float4*)&w2[(size_t)(i4 * 4 + k) * 512 + cg * 8 + 4];
          wv[k][0] = q0.x; wv[k][1] = q0.y; wv[k][2] = q0.z; wv[k][3] = q0.w;
          wv[k][4] = q1.x; wv[k][5] = q1.y; wv[k][6] = q1.z; wv[k][7] = q1.w;
        }
#pragma unroll
        for (int rr = 0; rr < 4; ++rr) {
          float4 aq = *(const float4*)&h[rg * 4 + rr][i4 * 4];
          float a[4] = {aq.x, aq.y, aq.z, aq.w};
#pragma unroll
          for (int k = 0; k < 4; ++k)
#pragma unroll
            for (int cc = 0; cc < 8; ++cc)
              acc[rr][cc] = fmaf(a[k], wv[k][cc], acc[rr][cc]);
        }
      }
      float mx[8];
#pragma unroll
      for (int cc = 0; cc < 8; ++cc) mx[cc] = -__builtin_inff();
#pragma unroll
      for (int rr = 0; rr < 4; ++rr) {
        if (ch * 16 + rg * 4 + rr < c) {
#pragma unroll
          for (int cc = 0; cc < 8; ++cc)
            mx[cc] = fmaxf(mx[cc], acc[rr][cc] + b2[cg * 8 + cc]);
        }
      }
#pragma unroll
      for (int cc = 0; cc < 8; ++cc) red[rg][cg * 8 + cc] = mx[cc];
    }
    __syncthreads();
    for (int k = t; k < 512; k += 256) {
      float v = omax[k];
#pragma unroll
      for (int g = 0; g < 4; ++g) v = fmaxf(v, red[g][k]);
      omax[k] = v;
    }
    __syncthreads();
  }
  out[(size_t)blk * 512 + t] = omax[t];
  out[(size_t)blk * 512 + t + 256] = omax[t + 256];
}

extern "C" void kernel_launch(void* const* d_in, const int* in_sizes, int n_in,
                              void* d_out, int out_size, void* d_ws, size_t ws_size,
                              hipStream_t stream) {
  const int* feat = (const int*)d_in[0];
  const float* pos = (const float*)d_in[1];
  const float* emb = (const float*)d_in[2];
  const float* pid = (const float*)d_in[3];
  const float* s1w0 = (const float*)d_in[4];
  const float* s1b0 = (const float*)d_in[5];
  const float* s1w1 = (const float*)d_in[6];
  const float* s1b1 = (const float*)d_in[7];
  const float* s1w2 = (const float*)d_in[8];
  const float* s1b2 = (const float*)d_in[9];
  const float* s2w0 = (const float*)d_in[10];
  const float* s2b0 = (const float*)d_in[11];
  const float* s2w1 = (const float*)d_in[12];
  const float* s2b1 = (const float*)d_in[13];
  const float* s2w2 = (const float*)d_in[14];
  const float* s2b2 = (const float*)d_in[15];
  const float* s3w0 = (const float*)d_in[16];
  const float* s3b0 = (const float*)d_in[17];
  const float* s3w1 = (const float*)d_in[18];
  const float* s3b1 = (const float*)d_in[19];
  const float* s3w2 = (const float*)d_in[20];
  const float* s3b2 = (const float*)d_in[21];
  (void)in_sizes; (void)n_in; (void)out_size; (void)ws_size;

  char* ws = (char*)d_ws;
  size_t off = 0;
  auto alloc = [&](size_t nbytes) {
    void* p = ws + off;
    off = (off + nbytes + 255) & ~(size_t)255;
    return p;
  };
  float* x0 = (float*)alloc((size_t)B * N0 * 32 * 4);
  float* pos1 = (float*)alloc((size_t)B * 1024 * 3 * 4);
  int* nbr1 = (int*)alloc((size_t)B * 1024 * KNB * 4);
  int* cnt1 = (int*)alloc((size_t)B * 1024 * 4);
  float* x1 = (float*)alloc((size_t)B * 1024 * 64 * 4);
  float* pos2 = (float*)alloc((size_t)B * 256 * 3 * 4);
  int* nbr2 = (int*)alloc((size_t)B * 256 * KNB * 4);
  int* cnt2 = (int*)alloc((size_t)B * 256 * 4);
  float* x2 = (float*)alloc((size_t)B * 256 * 256 * 4);
  int* nbr3 = (int*)alloc((size_t)B * 64 * KNB * 4);
  int* cnt3 = (int*)alloc((size_t)B * 64 * 4);

  float* xout = (float*)d_out;                 // (B,64,512)
  float* pos3 = xout + (size_t)B * 64 * 512;   // (B,64,3)

  const float r2a = (float)(0.05 * 0.05);
  const float r2b = (float)(0.3 * 0.3);
  const float r2c = (float)(0.5 * 0.5);

  x0_kernel<<<(B * N0 * 32 + 255) / 256, 256, 0, stream>>>(feat, emb, pid, x0);

  fps_kernel<4096, 1024, 512><<<B, 512, 0, stream>>>(pos, pos1);
  radius_kernel<4096, 1024><<<B * 1024, 256, 0, stream>>>(pos, pos1, r2a, nbr1, cnt1);
  conv1_kernel<<<B * 1024, 64, 0, stream>>>(x0, pos, pos1, nbr1, cnt1,
                                            s1w0, s1b0, s1w1, s1b1, s1w2, s1b2, x1);

  fps_kernel<1024, 256, 256><<<B, 256, 0, stream>>>(pos1, pos2);
  radius_kernel<1024, 256><<<B * 256, 256, 0, stream>>>(pos1, pos2, r2b, nbr2, cnt2);
  conv2_kernel<<<B * 256, 256, 0, stream>>>(x1, pos1, pos2, nbr2, cnt2,
                                            s2w0, s2b0, s2w1, s2b1, s2w2, s2b2, x2);

  fps_kernel<256, 64, 64><<<B, 64, 0, stream>>>(pos2, pos3);
  radius_kernel<256, 64><<<B * 64, 256, 0, stream>>>(pos2, pos3, r2c, nbr3, cnt3);
  conv3_kernel<<<B * 64, 256, 0, stream>>>(x2, pos2, pos3, nbr3, cnt3,
                                           s3w0, s3b0, s3w1, s3b1, s3w2, s3b2, xout);
}

// Round 3
// 1641.581 us; speedup vs baseline: 1.2169x; 1.1459x over previous
//
#include <hip/hip_runtime.h>

#define DEVI static __device__ __forceinline__

constexpr int B = 8;
constexpr int N0 = 4096;
constexpr int KNB = 64;

// d2 exactly as numpy: ((dx*dx + dy*dy) + dz*dz), no FMA contraction.
DEVI float dist2f(float ax, float ay, float az, float bx, float by, float bz) {
#pragma clang fp contract(off)
  float dx = ax - bx;
  float dy = ay - by;
  float dz = az - bz;
  return (dx * dx + dy * dy) + dz * dz;
}

// argmin key: min d wins, ties -> lowest index
DEVI unsigned long long packMinKey(float v, int i) {
  return ((unsigned long long)__float_as_uint(v) << 32) | (unsigned int)i;
}

// ---- DPP-based wave-64 reductions (VALU pipe, no LDS round-trips) ----
// Canonical GCN sequence: row_shr:1/2/4/8 then row_bcast:15 (rows 1,3) and
// row_bcast:31 (rows 2,3); total lands in lane 63. old = self, bound_ctrl off
// -> masked/invalid lanes keep their own key (no-op in max/min combine).
template <int CTRL, int RM, bool MAXR>
DEVI unsigned long long dppCombine(unsigned long long k) {
  unsigned int lo = (unsigned int)k, hi = (unsigned int)(k >> 32);
  unsigned int mlo = (unsigned int)__builtin_amdgcn_update_dpp(
      (int)lo, (int)lo, CTRL, RM, 0xf, false);
  unsigned int mhi = (unsigned int)__builtin_amdgcn_update_dpp(
      (int)hi, (int)hi, CTRL, RM, 0xf, false);
  unsigned long long o = ((unsigned long long)mhi << 32) | mlo;
  if (MAXR) return (k > o) ? k : o;
  return (k < o) ? k : o;
}
template <bool MAXR>
DEVI unsigned long long waveReduceU64(unsigned long long k) {
  k = dppCombine<0x111, 0xf, MAXR>(k);  // row_shr:1
  k = dppCombine<0x112, 0xf, MAXR>(k);  // row_shr:2
  k = dppCombine<0x114, 0xf, MAXR>(k);  // row_shr:4
  k = dppCombine<0x118, 0xf, MAXR>(k);  // row_shr:8
  k = dppCombine<0x142, 0xa, MAXR>(k);  // row_bcast:15 -> rows 1,3
  k = dppCombine<0x143, 0xc, MAXR>(k);  // row_bcast:31 -> rows 2,3
  unsigned int lo = (unsigned int)__builtin_amdgcn_readlane((int)(unsigned int)k, 63);
  unsigned int hi =
      (unsigned int)__builtin_amdgcn_readlane((int)(unsigned int)(k >> 32), 63);
  return ((unsigned long long)hi << 32) | lo;
}

// ---------------- embedding + point_id_emb ----------------
__global__ void __launch_bounds__(256) x0_kernel(const int* __restrict__ feat,
                                                 const float* __restrict__ emb,
                                                 const float* __restrict__ pid,
                                                 float* __restrict__ x0) {
  int gid = blockIdx.x * 256 + threadIdx.x;  // over B*N0*32
  if (gid >= B * N0 * 32) return;
  int c = gid & 31;
  int bn = gid >> 5;
  int n = bn & (N0 - 1);
  int f = feat[bn];
  float v = emb[f * 32 + c];
  if (n < 1024) v += pid[n * 32 + c];
  x0[gid] = v;
}

// ---------------- farthest point sampling (latency-optimized) ----------------
// Per iteration: register best-tracking -> DPP u64 argmax (VALU) ->
// cross-wave via LDS (1 barrier, double-buffered) -> selected pos from LDS
// float4 table (one ds_read_b128) -> distance update.
// Selection semantics identical to jnp.argmax (ties -> lowest index).
template <int NPTS, int M, int BLK>
__global__ void __launch_bounds__(BLK) fps_kernel(const float* __restrict__ pos,
                                                  float* __restrict__ pos_out) {
  constexpr int EPT = NPTS / BLK;
  constexpr int NW = BLK / 64;
  __shared__ float4 posl[NPTS];
  __shared__ unsigned long long red[2][NW < 2 ? 2 : NW];
  const int b = blockIdx.x;
  const int t = threadIdx.x;
  const float* pb = pos + (size_t)b * NPTS * 3;
  float px[EPT], py[EPT], pz[EPT], d[EPT];
#pragma unroll
  for (int e = 0; e < EPT; ++e) {
    int i = t + e * BLK;
    float x = pb[i * 3 + 0];
    float y = pb[i * 3 + 1];
    float z = pb[i * 3 + 2];
    px[e] = x; py[e] = y; pz[e] = z;
    posl[i] = make_float4(x, y, z, 0.f);
  }
  float sx = pb[0], sy = pb[1], sz = pb[2];
  if (t == 0) {
    pos_out[(size_t)(b * M) * 3 + 0] = sx;
    pos_out[(size_t)(b * M) * 3 + 1] = sy;
    pos_out[(size_t)(b * M) * 3 + 2] = sz;
  }
  float bestv = -1.f;  // all d2 >= 0
  int bestidx = 0;
#pragma unroll
  for (int e = 0; e < EPT; ++e) {
    float v = dist2f(px[e], py[e], pz[e], sx, sy, sz);
    d[e] = v;
    if (v > bestv) { bestv = v; bestidx = t + e * BLK; }  // strict > keeps lowest idx in-lane
  }
  for (int it = 1; it < M; ++it) {
    // pack: max d wins; ties -> lowest index via inverted low word
    unsigned long long k =
        ((unsigned long long)__float_as_uint(bestv) << 32) |
        (unsigned int)(0x7fffffff - bestidx);
    k = waveReduceU64<true>(k);
    if constexpr (NW > 1) {
      if ((t & 63) == 0) red[it & 1][t >> 6] = k;
      __syncthreads();
#pragma unroll
      for (int w = 0; w < NW; ++w) {
        unsigned long long o = red[it & 1][w];
        k = (k > o) ? k : o;
      }
    }
    const int sel = 0x7fffffff - (int)(unsigned int)(k & 0xffffffffULL);
    float4 sp = posl[sel];  // LDS broadcast
    if (t == 0) {
      pos_out[(size_t)(b * M + it) * 3 + 0] = sp.x;
      pos_out[(size_t)(b * M + it) * 3 + 1] = sp.y;
      pos_out[(size_t)(b * M + it) * 3 + 2] = sp.z;
    }
    bestv = -1.f;
    bestidx = 0;
#pragma unroll
    for (int e = 0; e < EPT; ++e) {
      float nd = dist2f(px[e], py[e], pz[e], sp.x, sp.y, sp.z);
      float v = fminf(d[e], nd);
      d[e] = v;
      if (v > bestv) { bestv = v; bestidx = t + e * BLK; }
    }
  }
}

// ---------------- radius neighbors (<=64 nearest within r) ----------------
template <int NPTS, int M>
__global__ void __launch_bounds__(256) radius_kernel(const float* __restrict__ pos,
                                                     const float* __restrict__ pos_s,
                                                     float r2,
                                                     int* __restrict__ nbr,
                                                     int* __restrict__ cnt) {
  __shared__ float d2s[NPTS];
  __shared__ unsigned long long red[4];
  __shared__ int ctr;
  const float INFV = __builtin_inff();
  const int blk = blockIdx.x;
  const int t = threadIdx.x;
  const int b = blk / M;
  const float* pb = pos + (size_t)b * NPTS * 3;
  const float cx = pos_s[(size_t)blk * 3 + 0];
  const float cy = pos_s[(size_t)blk * 3 + 1];
  const float cz = pos_s[(size_t)blk * 3 + 2];
  if (t == 0) ctr = 0;
  __syncthreads();
  for (int j = t; j < NPTS; j += 256) {
    float d2 = dist2f(pb[j * 3 + 0], pb[j * 3 + 1], pb[j * 3 + 2], cx, cy, cz);
    d2s[j] = (d2 <= r2) ? d2 : INFV;
  }
  __syncthreads();
  for (int j = t; j < NPTS; j += 256) {
    if (d2s[j] < INFV) {
      int p = atomicAdd(&ctr, 1);
      if (p < KNB) nbr[(size_t)blk * KNB + p] = j;
    }
  }
  __syncthreads();
  const int c = ctr;
  if (c <= KNB) {
    if (t == 0) cnt[blk] = c;
    return;
  }
  // overflow: exact 64-nearest, ties -> lower index (matches lax.top_k)
  for (int k = 0; k < KNB; ++k) {
    unsigned long long lk = ~0ULL;
    for (int j = t; j < NPTS; j += 256) {
      unsigned long long kk = packMinKey(d2s[j], j);
      lk = (lk < kk) ? lk : kk;
    }
    lk = waveReduceU64<false>(lk);
    if ((t & 63) == 0) red[t >> 6] = lk;
    __syncthreads();
#pragma unroll
    for (int w = 0; w < 4; ++w) {
      unsigned long long o = red[w];
      lk = (lk < o) ? lk : o;
    }
    int idx = (int)(unsigned int)(lk & 0xffffffffULL);
    if (t == 0) {
      nbr[(size_t)blk * KNB + k] = idx;
      d2s[idx] = INFV;
    }
    __syncthreads();
  }
  if (t == 0) cnt[blk] = KNB;
}

// ---------------- stage 1 conv: 35 -> 64 -> 64 -> 64, max over nbrs ----------------
__global__ void __launch_bounds__(64) conv1_kernel(
    const float* __restrict__ x0, const float* __restrict__ pos,
    const float* __restrict__ pos_s, const int* __restrict__ nbr,
    const int* __restrict__ cntp,
    const float* __restrict__ w0, const float* __restrict__ b0,
    const float* __restrict__ w1, const float* __restrict__ b1,
    const float* __restrict__ w2, const float* __restrict__ b2,
    float* __restrict__ x1) {
  __shared__ float ins[35];
  __shared__ float h[64];
  const int blk = blockIdx.x;  // B*1024
  const int t = threadIdx.x;
  const int b = blk >> 10;
  const int c = cntp[blk];
  const float cx = pos_s[(size_t)blk * 3 + 0];
  const float cy = pos_s[(size_t)blk * 3 + 1];
  const float cz = pos_s[(size_t)blk * 3 + 2];
  float best = -__builtin_inff();
  for (int r = 0; r < c; ++r) {
    int j = nbr[(size_t)blk * KNB + r];
    if (t < 32) {
      ins[t] = x0[((size_t)(b * N0) + j) * 32 + t];
    } else if (t < 35) {
      float pv = pos[((size_t)(b * N0) + j) * 3 + (t - 32)];
      float cv = (t == 32) ? cx : (t == 33) ? cy : cz;
      ins[t] = pv - cv;
    }
    __syncthreads();
    float v = b0[t];
#pragma unroll
    for (int i = 0; i < 35; ++i) v = fmaf(ins[i], w0[i * 64 + t], v);
    v = fmaxf(v, 0.f);
    h[t] = v;
    __syncthreads();
    float v2 = b1[t];
#pragma unroll
    for (int i = 0; i < 64; ++i) v2 = fmaf(h[i], w1[i * 64 + t], v2);
    v2 = fmaxf(v2, 0.f);
    __syncthreads();
    h[t] = v2;
    __syncthreads();
    float v3 = b2[t];
#pragma unroll
    for (int i = 0; i < 64; ++i) v3 = fmaf(h[i], w2[i * 64 + t], v3);
    best = fmaxf(best, v3);
    __syncthreads();
  }
  x1[(size_t)blk * 64 + t] = best;
}

// ---------------- stage 2 conv: 67 -> 128 -> 128 -> 256, max over nbrs ----------------
__global__ void __launch_bounds__(256) conv2_kernel(
    const float* __restrict__ x1, const float* __restrict__ pos1,
    const float* __restrict__ pos2, const int* __restrict__ nbr,
    const int* __restrict__ cntp,
    const float* __restrict__ w0, const float* __restrict__ b0,
    const float* __restrict__ w1, const float* __restrict__ b1,
    const float* __restrict__ w2, const float* __restrict__ b2,
    float* __restrict__ x2) {
  __shared__ __attribute__((aligned(16))) float msg[64][68];
  __shared__ __attribute__((aligned(16))) float h[64][128];
  __shared__ float red[8][256];
  const int blk = blockIdx.x;  // B*256
  const int t = threadIdx.x;
  const int b = blk >> 8;
  const int c = cntp[blk];
  const float cx = pos2[(size_t)blk * 3 + 0];
  const float cy = pos2[(size_t)blk * 3 + 1];
  const float cz = pos2[(size_t)blk * 3 + 2];
  for (int idx = t; idx < 64 * 68; idx += 256) {
    int r = idx / 68;
    int k = idx - r * 68;
    float v = 0.f;
    if (r < c && k < 67) {
      int j = nbr[(size_t)blk * KNB + r];
      if (k < 64) {
        v = x1[((size_t)(b * 1024) + j) * 64 + k];
      } else {
        float pv = pos1[((size_t)(b * 1024) + j) * 3 + (k - 64)];
        v = pv - ((k == 64) ? cx : (k == 65) ? cy : cz);
      }
    }
    msg[r][k] = v;
  }
  __syncthreads();
  const int rg = t >> 5;  // 8 row-groups of 8 rows
  const int cg = t & 31;
  // L1: K=67 -> h[64][128]
  {
    float acc[8][4] = {};
    for (int i4 = 0; i4 < 16; ++i4) {
      float wv[4][4];
#pragma unroll
      for (int k = 0; k < 4; ++k) {
        float4 q = *(const float4*)&w0[(size_t)(i4 * 4 + k) * 128 + cg * 4];
        wv[k][0] = q.x; wv[k][1] = q.y; wv[k][2] = q.z; wv[k][3] = q.w;
      }
#pragma unroll
      for (int rr = 0; rr < 8; ++rr) {
        float4 aq = *(const float4*)&msg[rg * 8 + rr][i4 * 4];
        float a[4] = {aq.x, aq.y, aq.z, aq.w};
#pragma unroll
        for (int k = 0; k < 4; ++k)
#pragma unroll
          for (int cc = 0; cc < 4; ++cc)
            acc[rr][cc] = fmaf(a[k], wv[k][cc], acc[rr][cc]);
      }
    }
#pragma unroll
    for (int i = 64; i < 67; ++i) {
      float wv[4];
#pragma unroll
      for (int cc = 0; cc < 4; ++cc) wv[cc] = w0[(size_t)i * 128 + cg * 4 + cc];
#pragma unroll
      for (int rr = 0; rr < 8; ++rr) {
        float a = msg[rg * 8 + rr][i];
#pragma unroll
        for (int cc = 0; cc < 4; ++cc) acc[rr][cc] = fmaf(a, wv[cc], acc[rr][cc]);
      }
    }
#pragma unroll
    for (int rr = 0; rr < 8; ++rr)
#pragma unroll
      for (int cc = 0; cc < 4; ++cc)
        h[rg * 8 + rr][cg * 4 + cc] = fmaxf(acc[rr][cc] + b0[cg * 4 + cc], 0.f);
  }
  __syncthreads();
  // L2: K=128, in-place on h
  {
    float acc[8][4] = {};
    for (int i4 = 0; i4 < 32; ++i4) {
      float wv[4][4];
#pragma unroll
      for (int k = 0; k < 4; ++k) {
        float4 q = *(const float4*)&w1[(size_t)(i4 * 4 + k) * 128 + cg * 4];
        wv[k][0] = q.x; wv[k][1] = q.y; wv[k][2] = q.z; wv[k][3] = q.w;
      }
#pragma unroll
      for (int rr = 0; rr < 8; ++rr) {
        float4 aq = *(const float4*)&h[rg * 8 + rr][i4 * 4];
        float a[4] = {aq.x, aq.y, aq.z, aq.w};
#pragma unroll
        for (int k = 0; k < 4; ++k)
#pragma unroll
          for (int cc = 0; cc < 4; ++cc)
            acc[rr][cc] = fmaf(a[k], wv[k][cc], acc[rr][cc]);
      }
    }
    __syncthreads();  // all reads of h done before overwrite
#pragma unroll
    for (int rr = 0; rr < 8; ++rr)
#pragma unroll
      for (int cc = 0; cc < 4; ++cc)
        h[rg * 8 + rr][cg * 4 + cc] = fmaxf(acc[rr][cc] + b1[cg * 4 + cc], 0.f);
  }
  __syncthreads();
  // L3: K=128 -> 64x256, then masked max over rows
  {
    float acc[8][8] = {};
    for (int i4 = 0; i4 < 32; ++i4) {
      float wv[4][8];
#pragma unroll
      for (int k = 0; k < 4; ++k) {
        float4 q0 = *(const float4*)&w2[(size_t)(i4 * 4 + k) * 256 + cg * 8];
        float4 q1 = *(const float4*)&w2[(size_t)(i4 * 4 + k) * 256 + cg * 8 + 4];
        wv[k][0] = q0.x; wv[k][1] = q0.y; wv[k][2] = q0.z; wv[k][3] = q0.w;
        wv[k][4] = q1.x; wv[k][5] = q1.y; wv[k][6] = q1.z; wv[k][7] = q1.w;
      }
#pragma unroll
      for (int rr = 0; rr < 8; ++rr) {
        float4 aq = *(const float4*)&h[rg * 8 + rr][i4 * 4];
        float a[4] = {aq.x, aq.y, aq.z, aq.w};
#pragma unroll
        for (int k = 0; k < 4; ++k)
#pragma unroll
          for (int cc = 0; cc < 8; ++cc)
            acc[rr][cc] = fmaf(a[k], wv[k][cc], acc[rr][cc]);
      }
    }
    float mx[8];
#pragma unroll
    for (int cc = 0; cc < 8; ++cc) mx[cc] = -__builtin_inff();
#pragma unroll
    for (int rr = 0; rr < 8; ++rr) {
      if (rg * 8 + rr < c) {
#pragma unroll
        for (int cc = 0; cc < 8; ++cc)
          mx[cc] = fmaxf(mx[cc], acc[rr][cc] + b2[cg * 8 + cc]);
      }
    }
#pragma unroll
    for (int cc = 0; cc < 8; ++cc) red[rg][cg * 8 + cc] = mx[cc];
  }
  __syncthreads();
  {
    float v = red[0][t];
#pragma unroll
    for (int g = 1; g < 8; ++g) v = fmaxf(v, red[g][t]);
    x2[(size_t)blk * 256 + t] = v;
  }
}

// ---------------- stage 3 conv: 259 -> 256 -> 512 -> 512, max over nbrs ----------------
__global__ void __launch_bounds__(256) conv3_kernel(
    const float* __restrict__ x2, const float* __restrict__ pos2,
    const float* __restrict__ pos3, const int* __restrict__ nbr,
    const int* __restrict__ cntp,
    const float* __restrict__ w0, const float* __restrict__ b0,
    const float* __restrict__ w1, const float* __restrict__ b1,
    const float* __restrict__ w2, const float* __restrict__ b2,
    float* __restrict__ out) {
  __shared__ __attribute__((aligned(16))) float msg[16][260];
  __shared__ __attribute__((aligned(16))) float h[16][512];
  __shared__ float red[4][512];
  __shared__ float omax[512];
  const int blk = blockIdx.x;  // B*64
  const int t = threadIdx.x;
  const int b = blk >> 6;
  const int c = cntp[blk];
  const float cx = pos3[(size_t)blk * 3 + 0];
  const float cy = pos3[(size_t)blk * 3 + 1];
  const float cz = pos3[(size_t)blk * 3 + 2];
  omax[t] = -__builtin_inff();
  omax[t + 256] = -__builtin_inff();
  const int rg = t >> 6;  // 4 row-groups of 4 rows
  const int cg = t & 63;
  __syncthreads();
  for (int ch = 0; ch < 4; ++ch) {
    if (ch * 16 >= c) break;
    for (int idx = t; idx < 16 * 260; idx += 256) {
      int r = idx / 260;
      int k = idx - r * 260;
      int rglob = ch * 16 + r;
      float v = 0.f;
      if (rglob < c && k < 259) {
        int j = nbr[(size_t)blk * KNB + rglob];
        if (k < 256) {
          v = x2[((size_t)(b * 256) + j) * 256 + k];
        } else {
          float pv = pos2[((size_t)(b * 256) + j) * 3 + (k - 256)];
          v = pv - ((k == 256) ? cx : (k == 257) ? cy : cz);
        }
      }
      msg[r][k] = v;
    }
    __syncthreads();
    // L1: 16x256, K=259
    {
      float acc[4][4] = {};
      for (int i4 = 0; i4 < 64; ++i4) {
        float wv[4][4];
#pragma unroll
        for (int k = 0; k < 4; ++k) {
          float4 q = *(const float4*)&w0[(size_t)(i4 * 4 + k) * 256 + cg * 4];
          wv[k][0] = q.x; wv[k][1] = q.y; wv[k][2] = q.z; wv[k][3] = q.w;
        }
#pragma unroll
        for (int rr = 0; rr < 4; ++rr) {
          float4 aq = *(const float4*)&msg[rg * 4 + rr][i4 * 4];
          float a[4] = {aq.x, aq.y, aq.z, aq.w};
#pragma unroll
          for (int k = 0; k < 4; ++k)
#pragma unroll
            for (int cc = 0; cc < 4; ++cc)
              acc[rr][cc] = fmaf(a[k], wv[k][cc], acc[rr][cc]);
        }
      }
#pragma unroll
      for (int i = 256; i < 259; ++i) {
        float wv[4];
#pragma unroll
        for (int cc = 0; cc < 4; ++cc) wv[cc] = w0[(size_t)i * 256 + cg * 4 + cc];
#pragma unroll
        for (int rr = 0; rr < 4; ++rr) {
          float a = msg[rg * 4 + rr][i];
#pragma unroll
          for (int cc = 0; cc < 4; ++cc) acc[rr][cc] = fmaf(a, wv[cc], acc[rr][cc]);
        }
      }
#pragma unroll
      for (int rr = 0; rr < 4; ++rr)
#pragma unroll
        for (int cc = 0; cc < 4; ++cc)
          h[rg * 4 + rr][cg * 4 + cc] = fmaxf(acc[rr][cc] + b0[cg * 4 + cc], 0.f);
    }
    __syncthreads();
    // L2: 16x512, K=256, in-place on h (read cols 0..255, write 0..511)
    {
      float acc[4][8] = {};
      for (int i4 = 0; i4 < 64; ++i4) {
        float wv[4][8];
#pragma unroll
        for (int k = 0; k < 4; ++k) {
          float4 q0 = *(const float4*)&w1[(size_t)(i4 * 4 + k) * 512 + cg * 8];
          float4 q1 = *(const float4*)&w1[(size_t)(i4 * 4 + k) * 512 + cg * 8 + 4];
          wv[k][0] = q0.x; wv[k][1] = q0.y; wv[k][2] = q0.z; wv[k][3] = q0.w;
          wv[k][4] = q1.x; wv[k][5] = q1.y; wv[k][6] = q1.z; wv[k][7] = q1.w;
        }
#pragma unroll
        for (int rr = 0; rr < 4; ++rr) {
          float4 aq = *(const float4*)&h[rg * 4 + rr][i4 * 4];
          float a[4] = {aq.x, aq.y, aq.z, aq.w};
#pragma unroll
          for (int k = 0; k < 4; ++k)
#pragma unroll
            for (int cc = 0; cc < 8; ++cc)
              acc[rr][cc] = fmaf(a[k], wv[k][cc], acc[rr][cc]);
        }
      }
      __syncthreads();
#pragma unroll
      for (int rr = 0; rr < 4; ++rr)
#pragma unroll
        for (int cc = 0; cc < 8; ++cc)
          h[rg * 4 + rr][cg * 8 + cc] = fmaxf(acc[rr][cc] + b1[cg * 8 + cc], 0.f);
    }
    __syncthreads();
    // L3: 16x512, K=512, masked max
    {
      float acc[4][8] = {};
      for (int i4 = 0; i4 < 128; ++i4) {
        float wv[4][8];
#pragma unroll
        for (int k = 0; k < 4; ++k) {
          float4 q0 = *(const float4*)&w2[(size_t)(i4 * 4 + k) * 512 + cg * 8];
          float4 q1 = *(const float4*)&w2[(size_t)(i4 * 4 + k) * 512 + cg * 8 + 4];
          wv[k][0] = q0.x; wv[k][1] = q0.y; wv[k][2] = q0.z; wv[k][3] = q0.w;
          wv[k][4] = q1.x; wv[k][5] = q1.y; wv[k][6] = q1.z; wv[k][7] = q1.w;
        }
#pragma unroll
        for (int rr = 0; rr < 4; ++rr) {
          float4 aq = *(const float4*)&h[rg * 4 + rr][i4 * 4];
          float a[4] = {aq.x, aq.y, aq.z, aq.w};
#pragma unroll
          for (int k = 0; k < 4; ++k)
#pragma unroll
            for (int cc = 0; cc < 8; ++cc)
              acc[rr][cc] = fmaf(a[k], wv[k][cc], acc[rr][cc]);
        }
      }
      float mx[8];
#pragma unroll
      for (int cc = 0; cc < 8; ++cc) mx[cc] = -__builtin_inff();
#pragma unroll
      for (int rr = 0; rr < 4; ++rr) {
        if (ch * 16 + rg * 4 + rr < c) {
#pragma unroll
          for (int cc = 0; cc < 8; ++cc)
            mx[cc] = fmaxf(mx[cc], acc[rr][cc] + b2[cg * 8 + cc]);
        }
      }
#pragma unroll
      for (int cc = 0; cc < 8; ++cc) red[rg][cg * 8 + cc] = mx[cc];
    }
    __syncthreads();
    for (int k = t; k < 512; k += 256) {
      float v = omax[k];
#pragma unroll
      for (int g = 0; g < 4; ++g) v = fmaxf(v, red[g][k]);
      omax[k] = v;
    }
    __syncthreads();
  }
  out[(size_t)blk * 512 + t] = omax[t];
  out[(size_t)blk * 512 + t + 256] = omax[t + 256];
}

extern "C" void kernel_launch(void* const* d_in, const int* in_sizes, int n_in,
                              void* d_out, int out_size, void* d_ws, size_t ws_size,
                              hipStream_t stream) {
  const int* feat = (const int*)d_in[0];
  const float* pos = (const float*)d_in[1];
  const float* emb = (const float*)d_in[2];
  const float* pid = (const float*)d_in[3];
  const float* s1w0 = (const float*)d_in[4];
  const float* s1b0 = (const float*)d_in[5];
  const float* s1w1 = (const float*)d_in[6];
  const float* s1b1 = (const float*)d_in[7];
  const float* s1w2 = (const float*)d_in[8];
  const float* s1b2 = (const float*)d_in[9];
  const float* s2w0 = (const float*)d_in[10];
  const float* s2b0 = (const float*)d_in[11];
  const float* s2w1 = (const float*)d_in[12];
  const float* s2b1 = (const float*)d_in[13];
  const float* s2w2 = (const float*)d_in[14];
  const float* s2b2 = (const float*)d_in[15];
  const float* s3w0 = (const float*)d_in[16];
  const float* s3b0 = (const float*)d_in[17];
  const float* s3w1 = (const float*)d_in[18];
  const float* s3b1 = (const float*)d_in[19];
  const float* s3w2 = (const float*)d_in[20];
  const float* s3b2 = (const float*)d_in[21];
  (void)in_sizes; (void)n_in; (void)out_size; (void)ws_size;

  char* ws = (char*)d_ws;
  size_t off = 0;
  auto alloc = [&](size_t nbytes) {
    void* p = ws + off;
    off = (off + nbytes + 255) & ~(size_t)255;
    return p;
  };
  float* x0 = (float*)alloc((size_t)B * N0 * 32 * 4);
  float* pos1 = (float*)alloc((size_t)B * 1024 * 3 * 4);
  int* nbr1 = (int*)alloc((size_t)B * 1024 * KNB * 4);
  int* cnt1 = (int*)alloc((size_t)B * 1024 * 4);
  float* x1 = (float*)alloc((size_t)B * 1024 * 64 * 4);
  float* pos2 = (float*)alloc((size_t)B * 256 * 3 * 4);
  int* nbr2 = (int*)alloc((size_t)B * 256 * KNB * 4);
  int* cnt2 = (int*)alloc((size_t)B * 256 * 4);
  float* x2 = (float*)alloc((size_t)B * 256 * 256 * 4);
  int* nbr3 = (int*)alloc((size_t)B * 64 * KNB * 4);
  int* cnt3 = (int*)alloc((size_t)B * 64 * 4);

  float* xout = (float*)d_out;                 // (B,64,512)
  float* pos3 = xout + (size_t)B * 64 * 512;   // (B,64,3)

  const float r2a = (float)(0.05 * 0.05);
  const float r2b = (float)(0.3 * 0.3);
  const float r2c = (float)(0.5 * 0.5);

  x0_kernel<<<(B * N0 * 32 + 255) / 256, 256, 0, stream>>>(feat, emb, pid, x0);

  fps_kernel<4096, 1024, 512><<<B, 512, 0, stream>>>(pos, pos1);
  radius_kernel<4096, 1024><<<B * 1024, 256, 0, stream>>>(pos, pos1, r2a, nbr1, cnt1);
  conv1_kernel<<<B * 1024, 64, 0, stream>>>(x0, pos, pos1, nbr1, cnt1,
                                            s1w0, s1b0, s1w1, s1b1, s1w2, s1b2, x1);

  fps_kernel<1024, 256, 256><<<B, 256, 0, stream>>>(pos1, pos2);
  radius_kernel<1024, 256><<<B * 256, 256, 0, stream>>>(pos1, pos2, r2b, nbr2, cnt2);
  conv2_kernel<<<B * 256, 256, 0, stream>>>(x1, pos1, pos2, nbr2, cnt2,
                                            s2w0, s2b0, s2w1, s2b1, s2w2, s2b2, x2);

  fps_kernel<256, 64, 64><<<B, 64, 0, stream>>>(pos2, pos3);
  radius_kernel<256, 64><<<B * 64, 256, 0, stream>>>(pos2, pos3, r2c, nbr3, cnt3);
  conv3_kernel<<<B * 64, 256, 0, stream>>>(x2, pos2, pos3, nbr3, cnt3,
                                           s3w0, s3b0, s3w1, s3b1, s3w2, s3b2, xout);
}